// Round 2
// baseline (622.180 us; speedup 1.0000x reference)
//
#include <hip/hip_runtime.h>
#include <stdint.h>

#define B_TOK 8192
#define DIN 1024
#define DHID 4096
#define DOUT 1024
#define NE 8

typedef __bf16 bf16x8 __attribute__((ext_vector_type(8)));
typedef float f32x4 __attribute__((ext_vector_type(4)));

__device__ __forceinline__ unsigned short f2bf(float f) {
  union { float f; unsigned u; } v; v.f = f;
  unsigned r = v.u + 0x7fffu + ((v.u >> 16) & 1u);  // RNE
  return (unsigned short)(r >> 16);
}

__device__ __forceinline__ void async16(const void* g, void* l) {
  __builtin_amdgcn_global_load_lds(
      (__attribute__((address_space(1))) void*)const_cast<void*>(g),
      (__attribute__((address_space(3))) void*)l, 16, 0, 0);
}

// ---------------- router: logits (fp64 acc), argmax, one-hot, x->bf16 ----------------
__global__ __launch_bounds__(256) void router_kernel(
    const float* __restrict__ x, const float* __restrict__ rw,
    const float* __restrict__ rb, float* __restrict__ oh,
    unsigned short* __restrict__ xb, int* __restrict__ idx,
    int* __restrict__ pos, int* __restrict__ counts)
{
  const int token = blockIdx.x * 4 + (threadIdx.x >> 6);
  const int lane = threadIdx.x & 63;
  const float* xrow = x + (size_t)token * DIN;
  double acc[NE];
#pragma unroll
  for (int e = 0; e < NE; ++e) acc[e] = 0.0;

#pragma unroll
  for (int j = 0; j < 4; ++j) {
    const int v4 = j * 64 + lane;                      // float4 index in row
    const float4 xv = ((const float4*)xrow)[v4];
    const float4* rwr = (const float4*)(rw + (size_t)v4 * 32);  // 4 rows x 8
#pragma unroll
    for (int c = 0; c < 4; ++c) {
      const float xs = (&xv.x)[c];
      const float4 w0 = rwr[c * 2 + 0];
      const float4 w1 = rwr[c * 2 + 1];
      acc[0] += (double)(xs * w0.x); acc[1] += (double)(xs * w0.y);
      acc[2] += (double)(xs * w0.z); acc[3] += (double)(xs * w0.w);
      acc[4] += (double)(xs * w1.x); acc[5] += (double)(xs * w1.y);
      acc[6] += (double)(xs * w1.z); acc[7] += (double)(xs * w1.w);
    }
    ushort4 us;
    us.x = f2bf(xv.x); us.y = f2bf(xv.y); us.z = f2bf(xv.z); us.w = f2bf(xv.w);
    ((ushort4*)(xb + (size_t)token * DIN))[v4] = us;
  }
#pragma unroll
  for (int off = 32; off > 0; off >>= 1)
#pragma unroll
    for (int e = 0; e < NE; ++e) acc[e] += __shfl_xor(acc[e], off, 64);

  if (lane == 0) {
    double best = -1e300; int be = 0;
#pragma unroll
    for (int e = 0; e < NE; ++e) {
      const double v = acc[e] + (double)rb[e];
      if (v > best) { best = v; be = e; }   // strict > == first-max (np argmax)
    }
    idx[token] = be;
    pos[token] = atomicAdd(&counts[be], 1);
    float* o = oh + (size_t)token * NE;
#pragma unroll
    for (int e = 0; e < NE; ++e) o[e] = (e == be) ? 1.f : 0.f;
  }
}

// ---------------- fp32 [K][N] -> bf16 [N][K] transpose-convert ----------------
__global__ __launch_bounds__(256) void transpose_bf16(
    const float* __restrict__ in, unsigned short* __restrict__ out, int K, int N)
{
  __shared__ float tile[64][65];
  const size_t mat = (size_t)blockIdx.z * (size_t)K * N;
  const int k0 = blockIdx.x * 64, n0 = blockIdx.y * 64;
  const int c = threadIdx.x & 63, r0 = threadIdx.x >> 6;
#pragma unroll
  for (int rr = 0; rr < 64; rr += 4)
    tile[rr + r0][c] = in[mat + (size_t)(k0 + rr + r0) * N + n0 + c];
  __syncthreads();
#pragma unroll
  for (int rr = 0; rr < 64; rr += 4) {
    const int n2 = rr + r0;
    out[mat + (size_t)(n0 + n2) * K + k0 + c] = f2bf(tile[c][n2]);
  }
}

// ---------------- tile schedule (single thread, trivial) ----------------
__global__ void slots_kernel(const int* __restrict__ counts, int* __restrict__ offsets,
                             int* __restrict__ slot_e, int* __restrict__ slot_g0,
                             int* __restrict__ slot_nr, int* __restrict__ nslots)
{
  int off = 0, s = 0;
  offsets[0] = 0;
  for (int e = 0; e < NE; ++e) {
    const int c = counts[e];
    for (int t = 0; t < c; t += 128) {
      slot_e[s] = e; slot_g0[s] = off + t;
      slot_nr[s] = (c - t < 128) ? (c - t) : 128;
      ++s;
    }
    off += c;
    offsets[e + 1] = off;
  }
  *nslots = s;
}

__global__ __launch_bounds__(256) void scatter_kernel(
    const int* __restrict__ idx, const int* __restrict__ pos,
    const int* __restrict__ offsets, int* __restrict__ perm)
{
  const int t = blockIdx.x * 256 + threadIdx.x;
  perm[offsets[idx[t]] + pos[t]] = t;
}

// ---------------- grouped expert GEMM: h[g] = x[perm[g]] @ W[e] + eb[e] ----------------
__global__ __launch_bounds__(256) void expert_gemm(
    const unsigned short* __restrict__ xb, const unsigned short* __restrict__ Wt,
    const float* __restrict__ eb, const int* __restrict__ perm,
    const int* __restrict__ slot_e, const int* __restrict__ slot_g0,
    const int* __restrict__ slot_nr, const int* __restrict__ nslots,
    unsigned short* __restrict__ h)
{
  const int s = blockIdx.x;
  if (s >= *nslots) return;
  const int e = slot_e[s];
  const int g0 = slot_g0[s];
  const int nr = slot_nr[s];
  const int n0 = blockIdx.y * 128;

  __shared__ __align__(16) unsigned short lsA[128 * 64];
  __shared__ __align__(16) unsigned short lsB[128 * 64];

  const int tid = threadIdx.x;
  const int w = tid >> 6, lane = tid & 63;
  const int rgrp = lane >> 3, cch = lane & 7;
  const int sw8 = (cch ^ rgrp) * 8;          // XOR-swizzled global k-chunk
  const int rowb = w * 32;

  int tok[4];
#pragma unroll
  for (int sub = 0; sub < 4; ++sub) {
    const int row = rowb + sub * 8 + rgrp;
    tok[sub] = (row < nr) ? perm[g0 + row] : -1;
  }
  const unsigned short* wb = Wt + (size_t)e * DHID * DIN;

  const f32x4 z = {0.f, 0.f, 0.f, 0.f};
  f32x4 acc[4][4];
#pragma unroll
  for (int i = 0; i < 4; ++i)
#pragma unroll
    for (int j = 0; j < 4; ++j) acc[i][j] = z;

  const int wm = (w & 1) * 64, wn = (w >> 1) * 64;
  const int quad = lane >> 4, l15 = lane & 15;
  int ma[4], nb[4];
#pragma unroll
  for (int i = 0; i < 4; ++i) { ma[i] = wm + i * 16 + l15; nb[i] = wn + i * 16 + l15; }

  for (int k0 = 0; k0 < DIN; k0 += 64) {
#pragma unroll
    for (int sub = 0; sub < 4; ++sub) {
      const int rbase = rowb + sub * 8;
      if (tok[sub] >= 0)
        async16(xb + (size_t)tok[sub] * DIN + k0 + sw8, &lsA[rbase * 64]);
      async16(wb + (size_t)(n0 + rbase + rgrp) * DIN + k0 + sw8, &lsB[rbase * 64]);
    }
    __syncthreads();
#pragma unroll
    for (int ks = 0; ks < 2; ++ks) {
      const int q = ks * 4 + quad;
      bf16x8 af[4], bfr[4];
#pragma unroll
      for (int i = 0; i < 4; ++i)
        af[i] = *(const bf16x8*)&lsA[ma[i] * 64 + ((q ^ (ma[i] & 7)) << 3)];
#pragma unroll
      for (int i = 0; i < 4; ++i)
        bfr[i] = *(const bf16x8*)&lsB[nb[i] * 64 + ((q ^ (nb[i] & 7)) << 3)];
#pragma unroll
      for (int i = 0; i < 4; ++i)
#pragma unroll
        for (int j = 0; j < 4; ++j)
          acc[i][j] = __builtin_amdgcn_mfma_f32_16x16x32_bf16(af[i], bfr[j], acc[i][j], 0, 0, 0);
    }
    __syncthreads();
  }

#pragma unroll
  for (int j = 0; j < 4; ++j) {
    const int col = n0 + nb[j];
    const float bias = eb[e * DHID + col];
#pragma unroll
    for (int i = 0; i < 4; ++i)
#pragma unroll
      for (int r2 = 0; r2 < 4; ++r2) {
        const int row = wm + i * 16 + quad * 4 + r2;   // C/D: row=(lane>>4)*4+reg, col=lane&15
        if (row < nr)
          h[(size_t)(g0 + row) * DHID + col] = f2bf(acc[i][j][r2] + bias);
      }
  }
}

// ---------------- projection GEMM: out[perm[g]] = h[g] @ P + pb ----------------
__global__ __launch_bounds__(256) void proj_gemm(
    const unsigned short* __restrict__ hm, const unsigned short* __restrict__ Pt,
    const float* __restrict__ pb, const int* __restrict__ perm,
    float* __restrict__ out)
{
  const int m0 = blockIdx.x * 128, n0 = blockIdx.y * 128;
  __shared__ __align__(16) unsigned short lsA[128 * 64];
  __shared__ __align__(16) unsigned short lsB[128 * 64];

  const int tid = threadIdx.x;
  const int w = tid >> 6, lane = tid & 63;
  const int rgrp = lane >> 3, cch = lane & 7;
  const int sw8 = (cch ^ rgrp) * 8;
  const int rowb = w * 32;

  const f32x4 z = {0.f, 0.f, 0.f, 0.f};
  f32x4 acc[4][4];
#pragma unroll
  for (int i = 0; i < 4; ++i)
#pragma unroll
    for (int j = 0; j < 4; ++j) acc[i][j] = z;

  const int wm = (w & 1) * 64, wn = (w >> 1) * 64;
  const int quad = lane >> 4, l15 = lane & 15;
  int ma[4], nb[4];
#pragma unroll
  for (int i = 0; i < 4; ++i) { ma[i] = wm + i * 16 + l15; nb[i] = wn + i * 16 + l15; }

  for (int k0 = 0; k0 < DHID; k0 += 64) {
#pragma unroll
    for (int sub = 0; sub < 4; ++sub) {
      const int rbase = rowb + sub * 8;
      async16(hm + (size_t)(m0 + rbase + rgrp) * DHID + k0 + sw8, &lsA[rbase * 64]);
      async16(Pt + (size_t)(n0 + rbase + rgrp) * DHID + k0 + sw8, &lsB[rbase * 64]);
    }
    __syncthreads();
#pragma unroll
    for (int ks = 0; ks < 2; ++ks) {
      const int q = ks * 4 + quad;
      bf16x8 af[4], bfr[4];
#pragma unroll
      for (int i = 0; i < 4; ++i)
        af[i] = *(const bf16x8*)&lsA[ma[i] * 64 + ((q ^ (ma[i] & 7)) << 3)];
#pragma unroll
      for (int i = 0; i < 4; ++i)
        bfr[i] = *(const bf16x8*)&lsB[nb[i] * 64 + ((q ^ (nb[i] & 7)) << 3)];
#pragma unroll
      for (int i = 0; i < 4; ++i)
#pragma unroll
        for (int j = 0; j < 4; ++j)
          acc[i][j] = __builtin_amdgcn_mfma_f32_16x16x32_bf16(af[i], bfr[j], acc[i][j], 0, 0, 0);
    }
    __syncthreads();
  }

#pragma unroll
  for (int i = 0; i < 4; ++i)
#pragma unroll
    for (int r2 = 0; r2 < 4; ++r2) {
      const int row = m0 + wm + i * 16 + quad * 4 + r2;
      const int orow = perm[row];
#pragma unroll
      for (int j = 0; j < 4; ++j) {
        const int col = n0 + nb[j];
        out[(size_t)orow * DOUT + col] = acc[i][j][r2] + pb[col];
      }
    }
}

extern "C" void kernel_launch(void* const* d_in, const int* in_sizes, int n_in,
                              void* d_out, int out_size, void* d_ws, size_t ws_size,
                              hipStream_t stream)
{
  const float* x  = (const float*)d_in[0];
  const float* rw = (const float*)d_in[1];
  const float* rb = (const float*)d_in[2];
  const float* ew = (const float*)d_in[3];
  const float* eb = (const float*)d_in[4];
  const float* pw = (const float*)d_in[5];
  const float* pb = (const float*)d_in[6];
  float* out = (float*)d_out;
  float* oh  = out + (size_t)B_TOK * DOUT;   // one-hot routing weights tail

  char* ws = (char*)d_ws;
  constexpr size_t OXB = 0;                                         // x bf16 [8192][1024]
  constexpr size_t OWT = OXB + (size_t)B_TOK * DIN * 2;             // W^T bf16 [8][4096][1024]
  constexpr size_t OPT = OWT + (size_t)NE * DHID * DIN * 2;         // P^T bf16 [1024][4096]
  constexpr size_t OH  = OPT + (size_t)DOUT * DHID * 2;             // h bf16 [8192][4096] (perm order)
  constexpr size_t OIDX = OH + (size_t)B_TOK * DHID * 2;
  constexpr size_t OPOS = OIDX + (size_t)B_TOK * 4;
  constexpr size_t OPRM = OPOS + (size_t)B_TOK * 4;
  constexpr size_t OCNT = OPRM + (size_t)B_TOK * 4;
  constexpr size_t OOFF = OCNT + 256;
  constexpr size_t OSE  = OOFF + 256;
  constexpr size_t OSG  = OSE + 512;
  constexpr size_t OSN  = OSG + 512;
  constexpr size_t ONS  = OSN + 512;
  constexpr size_t NEED = ONS + 512;

  // Workspace guard: if d_ws is too small, fail *cleanly* (zeroed output ->
  // absmax == stub signature) instead of faulting the container.
  if (ws_size < NEED) {
    hipMemsetAsync(d_out, 0, (size_t)out_size * 4, stream);
    return;
  }

  unsigned short* xb   = (unsigned short*)(ws + OXB);
  unsigned short* Wt   = (unsigned short*)(ws + OWT);
  unsigned short* Pt   = (unsigned short*)(ws + OPT);
  unsigned short* h    = (unsigned short*)(ws + OH);
  int* idx     = (int*)(ws + OIDX);
  int* pos     = (int*)(ws + OPOS);
  int* perm    = (int*)(ws + OPRM);
  int* counts  = (int*)(ws + OCNT);
  int* offsets = (int*)(ws + OOFF);
  int* slot_e  = (int*)(ws + OSE);
  int* slot_g0 = (int*)(ws + OSG);
  int* slot_nr = (int*)(ws + OSN);
  int* nslots  = (int*)(ws + ONS);

  hipMemsetAsync(counts, 0, 64, stream);
  router_kernel<<<B_TOK / 4, 256, 0, stream>>>(x, rw, rb, oh, xb, idx, pos, counts);
  transpose_bf16<<<dim3(DIN / 64, DHID / 64, NE), 256, 0, stream>>>(ew, Wt, DIN, DHID);
  transpose_bf16<<<dim3(DHID / 64, DOUT / 64, 1), 256, 0, stream>>>(pw, Pt, DHID, DOUT);
  slots_kernel<<<1, 1, 0, stream>>>(counts, offsets, slot_e, slot_g0, slot_nr, nslots);
  scatter_kernel<<<B_TOK / 256, 256, 0, stream>>>(idx, pos, offsets, perm);
  expert_gemm<<<dim3(64 + NE - 1, DHID / 128), 256, 0, stream>>>(
      xb, Wt, eb, perm, slot_e, slot_g0, slot_nr, nslots, h);
  proj_gemm<<<dim3(B_TOK / 128, DOUT / 128), 256, 0, stream>>>(h, Pt, pb, perm, out);
}

// Round 3
// 578.206 us; speedup vs baseline: 1.0761x; 1.0761x over previous
//
#include <hip/hip_runtime.h>
#include <stdint.h>

#define B_TOK 8192
#define DIN 1024
#define DHID 4096
#define DOUT 1024
#define NE 8

typedef __bf16 bf16x8 __attribute__((ext_vector_type(8)));
typedef float f32x4 __attribute__((ext_vector_type(4)));

__device__ __forceinline__ unsigned short f2bf(float f) {
  union { float f; unsigned u; } v; v.f = f;
  unsigned r = v.u + 0x7fffu + ((v.u >> 16) & 1u);  // RNE
  return (unsigned short)(r >> 16);
}

__device__ __forceinline__ void async16(const void* g, void* l) {
  __builtin_amdgcn_global_load_lds(
      (__attribute__((address_space(1))) void*)const_cast<void*>(g),
      (__attribute__((address_space(3))) void*)l, 16, 0, 0);
}

// ---------------- router: logits (fp64 acc), argmax, one-hot, x->bf16 ----------------
__global__ __launch_bounds__(256) void router_kernel(
    const float* __restrict__ x, const float* __restrict__ rw,
    const float* __restrict__ rb, float* __restrict__ oh,
    unsigned short* __restrict__ xb, int* __restrict__ idx,
    int* __restrict__ pos, int* __restrict__ counts)
{
  const int token = blockIdx.x * 4 + (threadIdx.x >> 6);
  const int lane = threadIdx.x & 63;
  const float* xrow = x + (size_t)token * DIN;
  double acc[NE];
#pragma unroll
  for (int e = 0; e < NE; ++e) acc[e] = 0.0;

#pragma unroll
  for (int j = 0; j < 4; ++j) {
    const int v4 = j * 64 + lane;                      // float4 index in row
    const float4 xv = ((const float4*)xrow)[v4];
    const float4* rwr = (const float4*)(rw + (size_t)v4 * 32);  // 4 rows x 8
#pragma unroll
    for (int c = 0; c < 4; ++c) {
      const float xs = (&xv.x)[c];
      const float4 w0 = rwr[c * 2 + 0];
      const float4 w1 = rwr[c * 2 + 1];
      acc[0] += (double)(xs * w0.x); acc[1] += (double)(xs * w0.y);
      acc[2] += (double)(xs * w0.z); acc[3] += (double)(xs * w0.w);
      acc[4] += (double)(xs * w1.x); acc[5] += (double)(xs * w1.y);
      acc[6] += (double)(xs * w1.z); acc[7] += (double)(xs * w1.w);
    }
    ushort4 us;
    us.x = f2bf(xv.x); us.y = f2bf(xv.y); us.z = f2bf(xv.z); us.w = f2bf(xv.w);
    ((ushort4*)(xb + (size_t)token * DIN))[v4] = us;
  }
#pragma unroll
  for (int off = 32; off > 0; off >>= 1)
#pragma unroll
    for (int e = 0; e < NE; ++e) acc[e] += __shfl_xor(acc[e], off, 64);

  if (lane == 0) {
    double best = -1e300; int be = 0;
#pragma unroll
    for (int e = 0; e < NE; ++e) {
      const double v = acc[e] + (double)rb[e];
      if (v > best) { best = v; be = e; }   // strict > == first-max (np argmax)
    }
    idx[token] = be;
    pos[token] = atomicAdd(&counts[be], 1);
    float* o = oh + (size_t)token * NE;
#pragma unroll
    for (int e = 0; e < NE; ++e) o[e] = (e == be) ? 1.f : 0.f;
  }
}

// ---------------- fp32 [K][N] -> bf16 [N][K] transpose-convert ----------------
__global__ __launch_bounds__(256) void transpose_bf16(
    const float* __restrict__ in, unsigned short* __restrict__ out, int K, int N)
{
  __shared__ float tile[64][65];
  const size_t mat = (size_t)blockIdx.z * (size_t)K * N;
  const int k0 = blockIdx.x * 64, n0 = blockIdx.y * 64;
  const int c = threadIdx.x & 63, r0 = threadIdx.x >> 6;
#pragma unroll
  for (int rr = 0; rr < 64; rr += 4)
    tile[rr + r0][c] = in[mat + (size_t)(k0 + rr + r0) * N + n0 + c];
  __syncthreads();
#pragma unroll
  for (int rr = 0; rr < 64; rr += 4) {
    const int n2 = rr + r0;
    out[mat + (size_t)(n0 + n2) * K + k0 + c] = f2bf(tile[c][n2]);
  }
}

// ---------------- tile schedule (single thread, trivial) ----------------
__global__ void slots_kernel(const int* __restrict__ counts, int* __restrict__ offsets,
                             int* __restrict__ slot_e, int* __restrict__ slot_g0,
                             int* __restrict__ slot_nr, int* __restrict__ nslots)
{
  int off = 0, s = 0;
  offsets[0] = 0;
  for (int e = 0; e < NE; ++e) {
    const int c = counts[e];
    for (int t = 0; t < c; t += 128) {
      slot_e[s] = e; slot_g0[s] = off + t;
      slot_nr[s] = (c - t < 128) ? (c - t) : 128;
      ++s;
    }
    off += c;
    offsets[e + 1] = off;
  }
  *nslots = s;
}

__global__ __launch_bounds__(256) void scatter_kernel(
    const int* __restrict__ idx, const int* __restrict__ pos,
    const int* __restrict__ offsets, int* __restrict__ perm)
{
  const int t = blockIdx.x * 256 + threadIdx.x;
  perm[offsets[idx[t]] + pos[t]] = t;
}

// ---------------- grouped expert GEMM: h[g] = x[perm[g]] @ W[e] + eb[e] ----------------
// 1D grid, id = slot*32 + ntile. B-tile sharers (8 slots of one expert, same
// ntile) sit at id-stride 32 == 0 mod 8 -> same XCD -> weight tile fetched
// once per XCD and served from that XCD's L2 (reuse distance ~4 local blocks).
__global__ __launch_bounds__(256) void expert_gemm(
    const unsigned short* __restrict__ xb, const unsigned short* __restrict__ Wt,
    const float* __restrict__ eb, const int* __restrict__ perm,
    const int* __restrict__ slot_e, const int* __restrict__ slot_g0,
    const int* __restrict__ slot_nr, const int* __restrict__ nslots,
    unsigned short* __restrict__ h)
{
  const int id = blockIdx.x;
  const int s = id >> 5;           // slot (M-tile)
  const int ntile = id & 31;       // N-tile
  if (s >= *nslots) return;
  const int e = slot_e[s];
  const int g0 = slot_g0[s];
  const int nr = slot_nr[s];
  const int n0 = ntile * 128;

  __shared__ __align__(16) unsigned short lsA[128 * 64];
  __shared__ __align__(16) unsigned short lsB[128 * 64];

  const int tid = threadIdx.x;
  const int w = tid >> 6, lane = tid & 63;
  const int rgrp = lane >> 3, cch = lane & 7;
  const int sw8 = (cch ^ rgrp) * 8;          // XOR-swizzled global k-chunk
  const int rowb = w * 32;

  int tok[4];
#pragma unroll
  for (int sub = 0; sub < 4; ++sub) {
    const int row = rowb + sub * 8 + rgrp;
    tok[sub] = (row < nr) ? perm[g0 + row] : -1;
  }
  const unsigned short* wb = Wt + (size_t)e * DHID * DIN;

  const f32x4 z = {0.f, 0.f, 0.f, 0.f};
  f32x4 acc[4][4];
#pragma unroll
  for (int i = 0; i < 4; ++i)
#pragma unroll
    for (int j = 0; j < 4; ++j) acc[i][j] = z;

  const int wm = (w & 1) * 64, wn = (w >> 1) * 64;
  const int quad = lane >> 4, l15 = lane & 15;
  int ma[4], nb[4];
#pragma unroll
  for (int i = 0; i < 4; ++i) { ma[i] = wm + i * 16 + l15; nb[i] = wn + i * 16 + l15; }

  for (int k0 = 0; k0 < DIN; k0 += 64) {
#pragma unroll
    for (int sub = 0; sub < 4; ++sub) {
      const int rbase = rowb + sub * 8;
      if (tok[sub] >= 0)
        async16(xb + (size_t)tok[sub] * DIN + k0 + sw8, &lsA[rbase * 64]);
      async16(wb + (size_t)(n0 + rbase + rgrp) * DIN + k0 + sw8, &lsB[rbase * 64]);
    }
    __syncthreads();
#pragma unroll
    for (int ks = 0; ks < 2; ++ks) {
      const int q = ks * 4 + quad;
      bf16x8 af[4], bfr[4];
#pragma unroll
      for (int i = 0; i < 4; ++i)
        af[i] = *(const bf16x8*)&lsA[ma[i] * 64 + ((q ^ (ma[i] & 7)) << 3)];
#pragma unroll
      for (int i = 0; i < 4; ++i)
        bfr[i] = *(const bf16x8*)&lsB[nb[i] * 64 + ((q ^ (nb[i] & 7)) << 3)];
#pragma unroll
      for (int i = 0; i < 4; ++i)
#pragma unroll
        for (int j = 0; j < 4; ++j)
          acc[i][j] = __builtin_amdgcn_mfma_f32_16x16x32_bf16(af[i], bfr[j], acc[i][j], 0, 0, 0);
    }
    __syncthreads();
  }

#pragma unroll
  for (int j = 0; j < 4; ++j) {
    const int col = n0 + nb[j];
    const float bias = eb[e * DHID + col];
#pragma unroll
    for (int i = 0; i < 4; ++i)
#pragma unroll
      for (int r2 = 0; r2 < 4; ++r2) {
        const int row = wm + i * 16 + quad * 4 + r2;   // C/D: row=(lane>>4)*4+reg, col=lane&15
        if (row < nr)
          h[(size_t)(g0 + row) * DHID + col] = f2bf(acc[i][j][r2] + bias);
      }
  }
}

// ---------------- projection GEMM: out[perm[g]] = h[g] @ P + pb ----------------
// 1D grid, id = ntile*64 + mtile. A(h)-tile sharers (same mtile, 8 ntiles) at
// id-stride 64 == 0 mod 8 -> same XCD -> h read once from HBM.
__global__ __launch_bounds__(256) void proj_gemm(
    const unsigned short* __restrict__ hm, const unsigned short* __restrict__ Pt,
    const float* __restrict__ pb, const int* __restrict__ perm,
    float* __restrict__ out)
{
  const int id = blockIdx.x;
  const int m0 = (id & 63) * 128;
  const int n0 = (id >> 6) * 128;
  __shared__ __align__(16) unsigned short lsA[128 * 64];
  __shared__ __align__(16) unsigned short lsB[128 * 64];

  const int tid = threadIdx.x;
  const int w = tid >> 6, lane = tid & 63;
  const int rgrp = lane >> 3, cch = lane & 7;
  const int sw8 = (cch ^ rgrp) * 8;
  const int rowb = w * 32;

  const f32x4 z = {0.f, 0.f, 0.f, 0.f};
  f32x4 acc[4][4];
#pragma unroll
  for (int i = 0; i < 4; ++i)
#pragma unroll
    for (int j = 0; j < 4; ++j) acc[i][j] = z;

  const int wm = (w & 1) * 64, wn = (w >> 1) * 64;
  const int quad = lane >> 4, l15 = lane & 15;
  int ma[4], nb[4];
#pragma unroll
  for (int i = 0; i < 4; ++i) { ma[i] = wm + i * 16 + l15; nb[i] = wn + i * 16 + l15; }

  for (int k0 = 0; k0 < DHID; k0 += 64) {
#pragma unroll
    for (int sub = 0; sub < 4; ++sub) {
      const int rbase = rowb + sub * 8;
      async16(hm + (size_t)(m0 + rbase + rgrp) * DHID + k0 + sw8, &lsA[rbase * 64]);
      async16(Pt + (size_t)(n0 + rbase + rgrp) * DHID + k0 + sw8, &lsB[rbase * 64]);
    }
    __syncthreads();
#pragma unroll
    for (int ks = 0; ks < 2; ++ks) {
      const int q = ks * 4 + quad;
      bf16x8 af[4], bfr[4];
#pragma unroll
      for (int i = 0; i < 4; ++i)
        af[i] = *(const bf16x8*)&lsA[ma[i] * 64 + ((q ^ (ma[i] & 7)) << 3)];
#pragma unroll
      for (int i = 0; i < 4; ++i)
        bfr[i] = *(const bf16x8*)&lsB[nb[i] * 64 + ((q ^ (nb[i] & 7)) << 3)];
#pragma unroll
      for (int i = 0; i < 4; ++i)
#pragma unroll
        for (int j = 0; j < 4; ++j)
          acc[i][j] = __builtin_amdgcn_mfma_f32_16x16x32_bf16(af[i], bfr[j], acc[i][j], 0, 0, 0);
    }
    __syncthreads();
  }

#pragma unroll
  for (int i = 0; i < 4; ++i)
#pragma unroll
    for (int r2 = 0; r2 < 4; ++r2) {
      const int row = m0 + wm + i * 16 + quad * 4 + r2;
      const int orow = perm[row];
#pragma unroll
      for (int j = 0; j < 4; ++j) {
        const int col = n0 + nb[j];
        out[(size_t)orow * DOUT + col] = acc[i][j][r2] + pb[col];
      }
    }
}

extern "C" void kernel_launch(void* const* d_in, const int* in_sizes, int n_in,
                              void* d_out, int out_size, void* d_ws, size_t ws_size,
                              hipStream_t stream)
{
  const float* x  = (const float*)d_in[0];
  const float* rw = (const float*)d_in[1];
  const float* rb = (const float*)d_in[2];
  const float* ew = (const float*)d_in[3];
  const float* eb = (const float*)d_in[4];
  const float* pw = (const float*)d_in[5];
  const float* pb = (const float*)d_in[6];
  float* out = (float*)d_out;
  float* oh  = out + (size_t)B_TOK * DOUT;   // one-hot routing weights tail

  char* ws = (char*)d_ws;
  constexpr size_t OXB = 0;                                         // x bf16 [8192][1024]
  constexpr size_t OWT = OXB + (size_t)B_TOK * DIN * 2;             // W^T bf16 [8][4096][1024]
  constexpr size_t OPT = OWT + (size_t)NE * DHID * DIN * 2;         // P^T bf16 [1024][4096]
  constexpr size_t OH  = OPT + (size_t)DOUT * DHID * 2;             // h bf16 [8192][4096] (perm order)
  constexpr size_t OIDX = OH + (size_t)B_TOK * DHID * 2;
  constexpr size_t OPOS = OIDX + (size_t)B_TOK * 4;
  constexpr size_t OPRM = OPOS + (size_t)B_TOK * 4;
  constexpr size_t OCNT = OPRM + (size_t)B_TOK * 4;
  constexpr size_t OOFF = OCNT + 256;
  constexpr size_t OSE  = OOFF + 256;
  constexpr size_t OSG  = OSE + 512;
  constexpr size_t OSN  = OSG + 512;
  constexpr size_t ONS  = OSN + 512;
  constexpr size_t NEED = ONS + 512;

  // Workspace guard: fail cleanly (zeroed output) instead of faulting.
  if (ws_size < NEED) {
    hipMemsetAsync(d_out, 0, (size_t)out_size * 4, stream);
    return;
  }

  unsigned short* xb   = (unsigned short*)(ws + OXB);
  unsigned short* Wt   = (unsigned short*)(ws + OWT);
  unsigned short* Pt   = (unsigned short*)(ws + OPT);
  unsigned short* h    = (unsigned short*)(ws + OH);
  int* idx     = (int*)(ws + OIDX);
  int* pos     = (int*)(ws + OPOS);
  int* perm    = (int*)(ws + OPRM);
  int* counts  = (int*)(ws + OCNT);
  int* offsets = (int*)(ws + OOFF);
  int* slot_e  = (int*)(ws + OSE);
  int* slot_g0 = (int*)(ws + OSG);
  int* slot_nr = (int*)(ws + OSN);
  int* nslots  = (int*)(ws + ONS);

  hipMemsetAsync(counts, 0, 64, stream);
  router_kernel<<<B_TOK / 4, 256, 0, stream>>>(x, rw, rb, oh, xb, idx, pos, counts);
  transpose_bf16<<<dim3(DIN / 64, DHID / 64, NE), 256, 0, stream>>>(ew, Wt, DIN, DHID);
  transpose_bf16<<<dim3(DHID / 64, DOUT / 64, 1), 256, 0, stream>>>(pw, Pt, DHID, DOUT);
  slots_kernel<<<1, 1, 0, stream>>>(counts, offsets, slot_e, slot_g0, slot_nr, nslots);
  scatter_kernel<<<B_TOK / 256, 256, 0, stream>>>(idx, pos, offsets, perm);
  // 72 slot capacity (64 full tiles + up to 7 expert-boundary partials, padded)
  expert_gemm<<<72 * 32, 256, 0, stream>>>(
      xb, Wt, eb, perm, slot_e, slot_g0, slot_nr, nslots, h);
  proj_gemm<<<(B_TOK / 128) * (DOUT / 128), 256, 0, stream>>>(h, Pt, pb, perm, out);
}